// Round 13
// baseline (137.495 us; speedup 1.0000x reference)
//
#include <hip/hip_runtime.h>

// NTN: out[n,k] = relu( cos(x1 @ W1[k], x2 @ W2[k]) + [x1,x2]·V[k] + b[k] )
// N=32768, D=128, K=16.
// R16 = R3 champion with e-split wave pairs: DS traffic halved, in-regime.
// Regime law (R3..R15): (256,2) + VGPR<=128 mandatory; stage must be the
// verbatim-R3 full-chunk form (16KB restage family failed twice, abandoned).
// Sum-of-pipes model: dur ~= DS 20.5 + MFMA 16.6 + VALU. Only untried
// in-regime lever: halve DS work. Block = 64 rows x 2 e-halves; wave (rw,eh)
// computes its 32 rows over e-tiles {2eh, 2eh+1} only -> 16 ds_read_b128 per
// chunk per wave (vs 32); each W fragment read by 2 waves (vs 4).
//  - grid 1024 = 512 rb(64 rows) x 2 kh; rowbase = rb*64 + rw*32.
//  - per-k cross-pair combine via scr[2][64][9] (stride 9: conflict-free):
//    odd wave writes folded partials after compute(h1); even wave combines +
//    stores at top of next iteration. Zero extra barriers; write->read and
//    read->rewrite separated by the two existing chunk barriers.
//  - stage/xb/accP/epilogue algebra verbatim from passing code.

typedef __attribute__((ext_vector_type(8))) __bf16 bf16x8;
typedef __attribute__((ext_vector_type(8))) unsigned short us8;
typedef __attribute__((ext_vector_type(4))) float f32x4;

static __device__ __forceinline__ unsigned short f2bf(float f) {
  unsigned u = __float_as_uint(f);
  u += 0x7FFFu + ((u >> 16) & 1u);   // round-to-nearest-even
  return (unsigned short)(u >> 16);
}

static __device__ __forceinline__ bf16x8 as_bf(us8 u) {
  bf16x8 r;
  __builtin_memcpy(&r, &u, sizeof(r));
  return r;
}

// ---------------- prep (R11 elementwise, UNCHANGED layouts) ----------------
// wsW[t*8+j] = f2bf(W_side[k][d = s*32 + q*8 + j][e = (h*4+et')*16 + l15])
//   t: u=t&2047, cc=t>>11; lane=u&63, s=(u>>6)&3, et'=(u>>8)&3, side=(u>>10)&1;
//   h=cc&1, k=cc>>1; q=lane>>4, l15=lane&15.
// wsV[u*8+j] = f2bf(V[l15*256 + cs*32 + q*8 + j]), u: lane=u&63, cs=u>>6.
__global__ void ntn_prep(const float* __restrict__ W1, const float* __restrict__ W2,
                         const float* __restrict__ V,
                         unsigned short* __restrict__ wsW, unsigned short* __restrict__ wsV) {
  int e2 = blockIdx.x * 256 + threadIdx.x;
  if (e2 < 524288) {
    int j = e2 & 7, t = e2 >> 3;
    int u = t & 2047, cc = t >> 11;
    int lane = u & 63, s = (u >> 6) & 3, et2 = (u >> 8) & 3, side = (u >> 10) & 1;
    int h = cc & 1, k = cc >> 1;
    int q = lane >> 4, l15 = lane & 15;
    int et = h * 4 + et2;
    const float* W = side ? W2 : W1;
    wsW[e2] = f2bf(W[k * 16384 + (s * 32 + q * 8 + j) * 128 + (et * 16 + l15)]);
  } else if (e2 < 528384) {
    int v2 = e2 - 524288;
    int j = v2 & 7, u = v2 >> 3;
    int lane = u & 63, cs = u >> 6;
    int q = lane >> 4, l15 = lane & 15;
    wsV[v2] = f2bf(V[l15 * 256 + cs * 32 + q * 8 + j]);
  }
}

// ---------------- main ----------------
__global__ __launch_bounds__(256, 2) void ntn_main(
    const float* __restrict__ x1, const float* __restrict__ x2,
    const float* __restrict__ b,
    const unsigned short* __restrict__ wsW, const unsigned short* __restrict__ wsV,
    float* __restrict__ out) {
  __shared__ uint4 ldsW[2][2048];    // two 32KB chunk slots = 64KB (R3 verbatim)
  __shared__ float scr[2][64][9];    // [rw][lane][nt*3+c] partials; stride 9 = conflict-free

  const int tid = threadIdx.x;
  const int lane = tid & 63, wave = tid >> 6;
  const int q = lane >> 4, l15 = lane & 15;
  const int rw = wave >> 1;          // row-group 0..1
  const int eh = wave & 1;           // e-half 0..1
  const int kh = blockIdx.x & 1;     // k range [8kh, 8kh+8)
  const int rb = blockIdx.x >> 1;    // 0..511: 64-row group
  const int rowbase = rb * 64 + rw * 32;

  const f32x4 zero4 = {0.f, 0.f, 0.f, 0.f};

  // async stage of one 32KB chunk into an LDS slot (R3 VERBATIM; all 4 waves)
  auto stage = [&](int cc, int slot) {
    const unsigned short* src = wsW + (size_t)cc * 16384 + (size_t)(wave * 512 + lane) * 8;
    uint4* dst = &ldsW[slot][wave * 512];
#pragma unroll
    for (int i = 0; i < 8; ++i)
      __builtin_amdgcn_global_load_lds(
          (__attribute__((address_space(1))) void*)(void*)(src + i * 512),
          (__attribute__((address_space(3))) void*)(dst + i * 64), 16, 0, 0);
  };

  stage(kh * 16, 0);   // first chunk of our k range

  // ---- X fragments (B-operand), bf16, k-invariant, in registers (verbatim) ----
  bf16x8 xb[2][2][4];
#pragma unroll
  for (int side = 0; side < 2; ++side) {
    const float* xp0 = side ? x2 : x1;
#pragma unroll
    for (int nt = 0; nt < 2; ++nt) {
#pragma unroll
      for (int s = 0; s < 4; ++s) {
        const float* p = xp0 + (size_t)(rowbase + nt * 16 + l15) * 128 + s * 32 + q * 8;
        float4 v0 = *(const float4*)p;
        float4 v1 = *(const float4*)(p + 4);
        us8 uu;
        uu[0] = f2bf(v0.x); uu[1] = f2bf(v0.y); uu[2] = f2bf(v0.z); uu[3] = f2bf(v0.w);
        uu[4] = f2bf(v1.x); uu[5] = f2bf(v1.y); uu[6] = f2bf(v1.z); uu[7] = f2bf(v1.w);
        xb[side][nt][s] = as_bf(uu);
      }
    }
  }

  // ---- part2 + b via MFMA (A = V frags; B = X frags), in registers (verbatim) ----
  f32x4 accP[2];
  {
    bf16x8 vf[8];
#pragma unroll
    for (int cs = 0; cs < 8; ++cs)
      vf[cs] = as_bf(*(const us8*)(wsV + (size_t)(cs * 64 + lane) * 8));
    float4 bv = *(const float4*)(b + q * 4);
#pragma unroll
    for (int nt = 0; nt < 2; ++nt) {
      f32x4 a = zero4;
#pragma unroll
      for (int cs = 0; cs < 8; ++cs)
        a = __builtin_amdgcn_mfma_f32_16x16x32_bf16(vf[cs], xb[cs >> 2][nt][cs & 3], a, 0, 0, 0);
      a.x += bv.x; a.y += bv.y; a.z += bv.z; a.w += bv.w;
      accP[nt] = a;   // lane quad q holds part2+b for k = q*4 + reg
    }
  }

  float nm[2] = {0.f, 0.f}, q1[2] = {0.f, 0.f}, q2[2] = {0.f, 0.f};

  // compute THIS WAVE'S e-half (2 e-tiles: et = eh*2 + e2) from an LDS slot.
  // Inner bodies verbatim R3; only the et subset differs.
  auto compute = [&](int slot) {
#pragma unroll
    for (int e2 = 0; e2 < 2; ++e2) {
      const int et = eh * 2 + e2;
      bf16x8 wa[4], wb[4];
#pragma unroll
      for (int s = 0; s < 4; ++s) {
        wa[s] = as_bf(*(const us8*)&ldsW[slot][et * 256 + s * 64 + lane]);
        wb[s] = as_bf(*(const us8*)&ldsW[slot][1024 + et * 256 + s * 64 + lane]);
      }
#pragma unroll
      for (int nt = 0; nt < 2; ++nt) {
        f32x4 a1 = zero4, a2 = zero4;
#pragma unroll
        for (int s = 0; s < 4; ++s)
          a1 = __builtin_amdgcn_mfma_f32_16x16x32_bf16(wa[s], xb[0][nt][s], a1, 0, 0, 0);
#pragma unroll
        for (int s = 0; s < 4; ++s)
          a2 = __builtin_amdgcn_mfma_f32_16x16x32_bf16(wb[s], xb[1][nt][s], a2, 0, 0, 0);
        nm[nt] += a1.x * a2.x + a1.y * a2.y + a1.z * a2.z + a1.w * a2.w;
        q1[nt] += a1.x * a1.x + a1.y * a1.y + a1.z * a1.z + a1.w * a1.w;
        q2[nt] += a2.x * a2.x + a2.y * a2.y + a2.z * a2.z + a2.w * a2.w;
      }
    }
  };

  // end-of-k: fold partials within wave; odd wave publishes to scratch and
  // resets; even wave holds folded partials in nm/q1/q2 across the barrier.
  auto foldk = [&]() {
#pragma unroll
    for (int nt = 0; nt < 2; ++nt) {
      float n = nm[nt], s1 = q1[nt], s2 = q2[nt];
      n  += __shfl_xor(n, 16);  n  += __shfl_xor(n, 32);
      s1 += __shfl_xor(s1, 16); s1 += __shfl_xor(s1, 32);
      s2 += __shfl_xor(s2, 16); s2 += __shfl_xor(s2, 32);
      if (eh == 1) {
        scr[rw][lane][nt * 3 + 0] = n;
        scr[rw][lane][nt * 3 + 1] = s1;
        scr[rw][lane][nt * 3 + 2] = s2;
        nm[nt] = 0.f; q1[nt] = 0.f; q2[nt] = 0.f;
      } else {
        nm[nt] = n; q1[nt] = s1; q2[nt] = s2;
      }
    }
  };

  // after the next barrier: even wave combines with partner partials + stores.
  auto finishk = [&](int kkp) {
    if (eh == 0) {
      const int k = kh * 8 + kkp;
      const int qo = k >> 2;
      const int r  = k & 3;
#pragma unroll
      for (int nt = 0; nt < 2; ++nt) {
        float n  = nm[nt] + scr[rw][lane][nt * 3 + 0];
        float s1 = q1[nt] + scr[rw][lane][nt * 3 + 1];
        float s2 = q2[nt] + scr[rw][lane][nt * 3 + 2];
        float d1 = fmaxf(sqrtf(s1), 1e-8f);
        float d2 = fmaxf(sqrtf(s2), 1e-8f);
        float p1 = n / (d1 * d2);
        float pc = (r == 0) ? accP[nt].x : (r == 1) ? accP[nt].y
                 : (r == 2) ? accP[nt].z : accP[nt].w;
        if (q == qo)
          out[(size_t)(rowbase + nt * 16 + l15) * 16 + k] = fmaxf(p1 + pc, 0.f);
        nm[nt] = 0.f; q1[nt] = 0.f; q2[nt] = 0.f;
      }
    }
  };

#pragma unroll 1
  for (int kk = 0; kk < 8; ++kk) {
    const int cbase = kh * 16 + 2 * kk;
    __syncthreads();                       // chunk (kk,h0) in slot0; scr(kk-1) visible
    if (kk > 0) finishk(kk - 1);           // reads scr; next scr write is after barrier (b)
    stage(cbase + 1, 1);
    compute(0);
    __syncthreads();                       // (b) chunk (kk,h1) in slot1; slot0 free
    if (kk < 7) stage(cbase + 2, 0);
    compute(1);
    foldk();                               // odd wave writes scr for k(kk)
  }
  __syncthreads();
  finishk(7);
}

extern "C" void kernel_launch(void* const* d_in, const int* in_sizes, int n_in,
                              void* d_out, int out_size, void* d_ws, size_t ws_size,
                              hipStream_t stream) {
  const float* x1 = (const float*)d_in[0];
  const float* x2 = (const float*)d_in[1];
  const float* W1 = (const float*)d_in[2];
  const float* W2 = (const float*)d_in[3];
  const float* V  = (const float*)d_in[4];
  const float* b  = (const float*)d_in[5];
  float* out = (float*)d_out;
  unsigned short* wsW = (unsigned short*)d_ws;
  unsigned short* wsV = wsW + (size_t)65536 * 8;   // 1MB offset

  ntn_prep<<<2064, 256, 0, stream>>>(W1, W2, V, wsW, wsV);
  ntn_main<<<1024, 256, 0, stream>>>(x1, x2, b, wsW, wsV, out);
}